// Round 3
// baseline (498.368 us; speedup 1.0000x reference)
//
#include <hip/hip_runtime.h>
#include <math.h>

// LinearAttentionBlock — bf16 MFMA, occupancy-optimized.
// B=16, N=8192, D=128, H=4, dh=32, FF=512. mfma_f32_16x16x32_bf16.
// kw: weights -> bf16 [n][k].
// k1: direct-from-global x frags; K=phi(x@Wk), V=x@Wv -> Kt/Vt LDS -> partial KV + Ksum.
//     LDS 36.8KB -> 4 blocks/CU.
// k2: reduce partials -> KVt bf16 [m][d], Ksum f32.
// k3: wave-private fused, zero barriers. y (LN1 out) spilled f32 into `out`
//     (scratch; overwritten by final store). LDS 36KB -> 4 blocks/CU.

using bfrag = __attribute__((ext_vector_type(8))) short;   // 8 bf16 (MFMA A/B)
using sh4   = __attribute__((ext_vector_type(4))) short;   // 4 bf16 (8B LDS write)
using ffrag = __attribute__((ext_vector_type(4))) float;   // MFMA C/D

#define MFMA(a, b, c) __builtin_amdgcn_mfma_f32_16x16x32_bf16((a), (b), (c), 0, 0, 0)

__device__ __forceinline__ float phi_fn(float v) { return v > 0.f ? v + 1.f : __expf(v); }

__device__ __forceinline__ short f2bf(float f) {
    union { float f; unsigned u; } v; v.f = f;
    unsigned r = v.u + 0x7fffu + ((v.u >> 16) & 1u);  // RNE
    return (short)(r >> 16);
}
__device__ __forceinline__ float bf2f(short s) {
    union { unsigned u; float f; } v; v.u = ((unsigned)(unsigned short)s) << 16;
    return v.f;
}

// ---------------- kw: weight convert + transpose ----------------
__global__ void kw_conv(const float* __restrict__ Wq, const float* __restrict__ Wk,
                        const float* __restrict__ Wv, const float* __restrict__ Wo,
                        const float* __restrict__ W1, const float* __restrict__ W2,
                        short* __restrict__ Wqt, short* __restrict__ Wkt,
                        short* __restrict__ Wvt, short* __restrict__ Wot,
                        short* __restrict__ W1t, short* __restrict__ W2t) {
    int i = blockIdx.x * 256 + threadIdx.x;
    if (i < 65536) {
        int mat = i >> 14, q = i & 16383, n = q >> 7, k = q & 127;
        const float* S = mat == 0 ? Wq : mat == 1 ? Wk : mat == 2 ? Wv : Wo;
        short* D = mat == 0 ? Wqt : mat == 1 ? Wkt : mat == 2 ? Wvt : Wot;
        D[n * 128 + k] = f2bf(S[k * 128 + n]);
    } else if (i < 131072) {
        int q = i - 65536, n = q >> 7, k = q & 127;
        W1t[n * 128 + k] = f2bf(W1[k * 512 + n]);
    } else {
        int q = i - 131072, n = q >> 9, k = q & 511;
        W2t[n * 512 + k] = f2bf(W2[k * 128 + n]);
    }
}

// ---------------- k1: K/V proj + partial KV ----------------
// G blocks x 256 thr; 64*nsub tokens/block; wave w = head w, owns 16 token rows per subtile.
__global__ __launch_bounds__(256, 4) void k1_kv(
    const float* __restrict__ x, const short* __restrict__ Wkt,
    const short* __restrict__ Wvt, short* __restrict__ partKV,
    float* __restrict__ partKs, int bpb_shift, int nsub) {
    __shared__ short Kt[128][72];  // [dim][token], 144B rows (16B-aligned, 2-way-free banks)
    __shared__ short Vt[128][72];

    const int t = threadIdx.x, w = t >> 6, l = t & 63, lr = l & 15, lg = l >> 4;
    const int blk = blockIdx.x, b = blk >> bpb_shift, tile = blk & ((1 << bpb_shift) - 1);
    const size_t tok0 = ((size_t)b << 13) + (size_t)tile * (64 * nsub);

    ffrag kvacc[2][2];
#pragma unroll
    for (int dt = 0; dt < 2; dt++)
#pragma unroll
        for (int mt = 0; mt < 2; mt++) kvacc[dt][mt] = ffrag{0.f, 0.f, 0.f, 0.f};
    float accKs[8];
#pragma unroll
    for (int i = 0; i < 8; i++) accKs[i] = 0.f;

    for (int s = 0; s < nsub; ++s) {
        // direct-from-global A-fragments for this wave's 16 token rows
        const float* xr = x + (tok0 + (size_t)s * 64 + w * 16 + lr) * 128;
        bfrag xf[4];
#pragma unroll
        for (int kk = 0; kk < 4; kk++) {
            const float4* p = (const float4*)(xr + kk * 32 + lg * 8);
            float4 v0 = p[0], v1 = p[1];
            bfrag sv;
            sv[0] = f2bf(v0.x); sv[1] = f2bf(v0.y); sv[2] = f2bf(v0.z); sv[3] = f2bf(v0.w);
            sv[4] = f2bf(v1.x); sv[5] = f2bf(v1.y); sv[6] = f2bf(v1.z); sv[7] = f2bf(v1.w);
            xf[kk] = sv;
        }
        const int toff = w * 16 + lg * 4;
#pragma unroll
        for (int n0 = 0; n0 < 8; n0++) {
            ffrag ck = {0.f, 0.f, 0.f, 0.f}, cv = {0.f, 0.f, 0.f, 0.f};
#pragma unroll
            for (int kk = 0; kk < 4; kk++) {
                bfrag bk = *(const bfrag*)(Wkt + (n0 * 16 + lr) * 128 + kk * 32 + lg * 8);
                bfrag bv = *(const bfrag*)(Wvt + (n0 * 16 + lr) * 128 + kk * 32 + lg * 8);
                ck = MFMA(xf[kk], bk, ck);
                cv = MFMA(xf[kk], bv, cv);
            }
            sh4 ks, vs;
#pragma unroll
            for (int j = 0; j < 4; j++) {
                float pv = phi_fn(ck[j]);
                accKs[n0] += pv;
                ks[j] = f2bf(pv);
                vs[j] = f2bf(cv[j]);
            }
            *(sh4*)&Kt[n0 * 16 + lr][toff] = ks;
            *(sh4*)&Vt[n0 * 16 + lr][toff] = vs;
        }
        __syncthreads();
        // KV accumulate over 64 tokens: A=Kt rows (head-w dims), B=Vt rows
#pragma unroll
        for (int kk = 0; kk < 2; kk++) {
            bfrag ka0 = *(const bfrag*)&Kt[w * 32 + lr][kk * 32 + lg * 8];
            bfrag ka1 = *(const bfrag*)&Kt[w * 32 + 16 + lr][kk * 32 + lg * 8];
            bfrag vb0 = *(const bfrag*)&Vt[w * 32 + lr][kk * 32 + lg * 8];
            bfrag vb1 = *(const bfrag*)&Vt[w * 32 + 16 + lr][kk * 32 + lg * 8];
            kvacc[0][0] = MFMA(ka0, vb0, kvacc[0][0]);
            kvacc[0][1] = MFMA(ka0, vb1, kvacc[0][1]);
            kvacc[1][0] = MFMA(ka1, vb0, kvacc[1][0]);
            kvacc[1][1] = MFMA(ka1, vb1, kvacc[1][1]);
        }
        __syncthreads();
    }
    short* pk = partKV + ((size_t)(blk * 4 + w) << 10);
#pragma unroll
    for (int dt = 0; dt < 2; dt++)
#pragma unroll
        for (int mt = 0; mt < 2; mt++)
#pragma unroll
            for (int j = 0; j < 4; j++)
                pk[(dt * 16 + lg * 4 + j) * 32 + mt * 16 + lr] = f2bf(kvacc[dt][mt][j]);
#pragma unroll
    for (int n0 = 0; n0 < 8; n0++) {
        float v = accKs[n0];
        v += __shfl_xor(v, 16);
        v += __shfl_xor(v, 32);
        if (l < 16) partKs[(blk * 4 + w) * 128 + n0 * 16 + l] = v;
    }
}

// ---------------- k2: reduce partials ----------------
__global__ void k2_red(const short* __restrict__ partKV, const float* __restrict__ partKs,
                       short* __restrict__ KVt, float* __restrict__ Ksf, int bpb) {
    int bh = blockIdx.x, b = bh >> 2, h = bh & 3, t = threadIdx.x;
    for (int idx = t; idx < 1024; idx += 256) {
        int d = idx >> 5, m = idx & 31;
        float s = 0.f;
        for (int i = 0; i < bpb; i++)
            s += bf2f(partKV[((size_t)((b * bpb + i) * 4 + h) << 10) + idx]);
        KVt[((size_t)bh << 10) + m * 32 + d] = f2bf(s);  // transposed [m][d]
    }
    if (t < 32) {
        float s = 0.f;
        for (int i = 0; i < bpb; i++)
            for (int w = 0; w < 4; w++)
                s += partKs[((b * bpb + i) * 4 + w) * 128 + h * 32 + t];
        Ksf[bh * 32 + t] = s;
    }
}

// ---------------- k3: fused main (zero barriers; wave-private; 36KB LDS) ----------------
// 1024 blocks x 256 thr; 128 tokens/block; wave w owns rows 32w..32w+31.
__global__ __launch_bounds__(256, 4) void k3_main(
    const float* __restrict__ x, const short* __restrict__ Wqt,
    const short* __restrict__ Wot, const short* __restrict__ KVt,
    const float* __restrict__ Ksf, const float* __restrict__ ln1g,
    const float* __restrict__ ln1b, const short* __restrict__ W1t,
    const float* __restrict__ b1, const short* __restrict__ W2t,
    const float* __restrict__ b2, const float* __restrict__ ln2g,
    const float* __restrict__ ln2b, float* __restrict__ out) {
    __shared__ short sbuf[128][136];  // Q -> attn -> y -> h chunks
    __shared__ float den[128][4];

    const int t = threadIdx.x, w = t >> 6, l = t & 63, lr = l & 15, lg = l >> 4;
    const int blk = blockIdx.x, b = blk >> 6;
    const size_t tok0 = ((size_t)b << 13) + (size_t)(blk & 63) * 128;
    const int R0 = w * 32;

    // ---- x A-fragments direct from global ----
    bfrag xf[2][4];
#pragma unroll
    for (int rt = 0; rt < 2; rt++) {
        const float* xr = x + (tok0 + R0 + rt * 16 + lr) * 128;
#pragma unroll
        for (int kk = 0; kk < 4; kk++) {
            const float4* p = (const float4*)(xr + kk * 32 + lg * 8);
            float4 v0 = p[0], v1 = p[1];
            bfrag sv;
            sv[0] = f2bf(v0.x); sv[1] = f2bf(v0.y); sv[2] = f2bf(v0.z); sv[3] = f2bf(v0.w);
            sv[4] = f2bf(v1.x); sv[5] = f2bf(v1.y); sv[6] = f2bf(v1.z); sv[7] = f2bf(v1.w);
            xf[rt][kk] = sv;
        }
    }

    // ---- Q = phi(x@Wq) -> sbuf ----
#pragma unroll
    for (int n0 = 0; n0 < 8; n0++) {
        ffrag c0 = {0.f, 0.f, 0.f, 0.f}, c1 = {0.f, 0.f, 0.f, 0.f};
#pragma unroll
        for (int kk = 0; kk < 4; kk++) {
            bfrag bw = *(const bfrag*)(Wqt + (n0 * 16 + lr) * 128 + kk * 32 + lg * 8);
            c0 = MFMA(xf[0][kk], bw, c0);
            c1 = MFMA(xf[1][kk], bw, c1);
        }
#pragma unroll
        for (int j = 0; j < 4; j++) {
            sbuf[R0 + lg * 4 + j][n0 * 16 + lr] = f2bf(phi_fn(c0[j]));
            sbuf[R0 + 16 + lg * 4 + j][n0 * 16 + lr] = f2bf(phi_fn(c1[j]));
        }
    }

    // ---- attn per head: denom (shfl) + Q@KV, in place over Q ----
#pragma unroll
    for (int h = 0; h < 4; h++) {
        bfrag qf0 = *(const bfrag*)&sbuf[R0 + lr][h * 32 + lg * 8];
        bfrag qf1 = *(const bfrag*)&sbuf[R0 + 16 + lr][h * 32 + lg * 8];
        const float4* kp = (const float4*)(Ksf + (b * 4 + h) * 32 + lg * 8);
        float4 ka = kp[0], kb = kp[1];
        float ksv[8] = {ka.x, ka.y, ka.z, ka.w, kb.x, kb.y, kb.z, kb.w};
        float p0 = 0.f, p1 = 0.f;
#pragma unroll
        for (int j = 0; j < 8; j++) {
            p0 += bf2f(qf0[j]) * ksv[j];
            p1 += bf2f(qf1[j]) * ksv[j];
        }
        p0 += __shfl_xor(p0, 16); p0 += __shfl_xor(p0, 32);
        p1 += __shfl_xor(p1, 16); p1 += __shfl_xor(p1, 32);
        if (l < 16) {
            den[R0 + l][h] = fmaxf(p0, 1e-6f);
            den[R0 + 16 + l][h] = fmaxf(p1, 1e-6f);
        }
        const ffrag fz = {0.f, 0.f, 0.f, 0.f};
#pragma unroll
        for (int mt = 0; mt < 2; mt++) {
            bfrag bkv = *(const bfrag*)(KVt + ((size_t)(b * 4 + h) << 10) + (mt * 16 + lr) * 32 + lg * 8);
            ffrag c0 = MFMA(qf0, bkv, fz);
            ffrag c1 = MFMA(qf1, bkv, fz);
#pragma unroll
            for (int j = 0; j < 4; j++) {
                int row0 = R0 + lg * 4 + j;
                int row1 = R0 + 16 + lg * 4 + j;
                sbuf[row0][h * 32 + mt * 16 + lr] = f2bf(c0[j] / den[row0][h]);
                sbuf[row1][h * 32 + mt * 16 + lr] = f2bf(c1[j] / den[row1][h]);
            }
        }
    }

    // ---- Wo + residual (f32 x re-read) + LN1 ----
    bfrag af[2][4];
#pragma unroll
    for (int rt = 0; rt < 2; rt++)
#pragma unroll
        for (int kk = 0; kk < 4; kk++)
            af[rt][kk] = *(const bfrag*)&sbuf[R0 + rt * 16 + lr][kk * 32 + lg * 8];
    float r[2][8][4];
#pragma unroll
    for (int n0 = 0; n0 < 8; n0++) {
        ffrag c0 = {0.f, 0.f, 0.f, 0.f}, c1 = {0.f, 0.f, 0.f, 0.f};
#pragma unroll
        for (int kk = 0; kk < 4; kk++) {
            bfrag bw = *(const bfrag*)(Wot + (n0 * 16 + lr) * 128 + kk * 32 + lg * 8);
            c0 = MFMA(af[0][kk], bw, c0);
            c1 = MFMA(af[1][kk], bw, c1);
        }
#pragma unroll
        for (int j = 0; j < 4; j++) {
            r[0][n0][j] = c0[j] + x[(tok0 + R0 + lg * 4 + j) * 128 + n0 * 16 + lr];
            r[1][n0][j] = c1[j] + x[(tok0 + R0 + 16 + lg * 4 + j) * 128 + n0 * 16 + lr];
        }
    }
    float mu[2][4], rs[2][4];
#pragma unroll
    for (int rt = 0; rt < 2; rt++)
#pragma unroll
        for (int j = 0; j < 4; j++) {
            float s1 = 0.f, s2 = 0.f;
#pragma unroll
            for (int n0 = 0; n0 < 8; n0++) { float v = r[rt][n0][j]; s1 += v; s2 += v * v; }
#pragma unroll
            for (int d = 1; d < 16; d <<= 1) { s1 += __shfl_xor(s1, d); s2 += __shfl_xor(s2, d); }
            float m_ = s1 * (1.f / 128.f);
            mu[rt][j] = m_;
            rs[rt][j] = rsqrtf(s2 * (1.f / 128.f) - m_ * m_ + 1e-5f);
        }
    // y -> sbuf (bf16, for FF fragments) and out (f32 scratch, for residual2)
#pragma unroll
    for (int n0 = 0; n0 < 8; n0++) {
        int c = n0 * 16 + lr;
        float g = ln1g[c], bb = ln1b[c];
#pragma unroll
        for (int rt = 0; rt < 2; rt++)
#pragma unroll
            for (int j = 0; j < 4; j++) {
                int row = R0 + rt * 16 + lg * 4 + j;
                float yv = (r[rt][n0][j] - mu[rt][j]) * rs[rt][j] * g + bb;
                sbuf[row][c] = f2bf(yv);
                out[(tok0 + row) * 128 + c] = yv;
            }
    }

    // ---- FF: h = relu(y@W1+b1) (4 chunks), f = h@W2 accumulated ----
    bfrag yf[2][4];
#pragma unroll
    for (int rt = 0; rt < 2; rt++)
#pragma unroll
        for (int kk = 0; kk < 4; kk++)
            yf[rt][kk] = *(const bfrag*)&sbuf[R0 + rt * 16 + lr][kk * 32 + lg * 8];
    ffrag facc[2][8];
#pragma unroll
    for (int rt = 0; rt < 2; rt++)
#pragma unroll
        for (int n0 = 0; n0 < 8; n0++) facc[rt][n0] = ffrag{0.f, 0.f, 0.f, 0.f};
    for (int ch = 0; ch < 4; ++ch) {
#pragma unroll
        for (int n0 = 0; n0 < 8; n0++) {
            ffrag c0 = {0.f, 0.f, 0.f, 0.f}, c1 = {0.f, 0.f, 0.f, 0.f};
#pragma unroll
            for (int kk = 0; kk < 4; kk++) {
                bfrag bw = *(const bfrag*)(W1t + (ch * 128 + n0 * 16 + lr) * 128 + kk * 32 + lg * 8);
                c0 = MFMA(yf[0][kk], bw, c0);
                c1 = MFMA(yf[1][kk], bw, c1);
            }
            float bb = b1[ch * 128 + n0 * 16 + lr];
#pragma unroll
            for (int j = 0; j < 4; j++) {
                sbuf[R0 + lg * 4 + j][n0 * 16 + lr] = f2bf(fmaxf(c0[j] + bb, 0.f));
                sbuf[R0 + 16 + lg * 4 + j][n0 * 16 + lr] = f2bf(fmaxf(c1[j] + bb, 0.f));
            }
        }
        bfrag hf[2][4];
#pragma unroll
        for (int rt = 0; rt < 2; rt++)
#pragma unroll
            for (int kk = 0; kk < 4; kk++)
                hf[rt][kk] = *(const bfrag*)&sbuf[R0 + rt * 16 + lr][kk * 32 + lg * 8];
#pragma unroll
        for (int n0 = 0; n0 < 8; n0++) {
#pragma unroll
            for (int kk = 0; kk < 4; kk++) {
                bfrag bw = *(const bfrag*)(W2t + (n0 * 16 + lr) * 512 + ch * 128 + kk * 32 + lg * 8);
                facc[0][n0] = MFMA(hf[0][kk], bw, facc[0][n0]);
                facc[1][n0] = MFMA(hf[1][kk], bw, facc[1][n0]);
            }
        }
    }

    // ---- residual2 (y from out scratch, f32) + LN2 + final store ----
#pragma unroll
    for (int n0 = 0; n0 < 8; n0++) {
        int c = n0 * 16 + lr;
        float bb = b2[c];
#pragma unroll
        for (int rt = 0; rt < 2; rt++)
#pragma unroll
            for (int j = 0; j < 4; j++) {
                int row = R0 + rt * 16 + lg * 4 + j;
                facc[rt][n0][j] = facc[rt][n0][j] + out[(tok0 + row) * 128 + c] + bb;
            }
    }
#pragma unroll
    for (int rt = 0; rt < 2; rt++)
#pragma unroll
        for (int j = 0; j < 4; j++) {
            float s1 = 0.f, s2 = 0.f;
#pragma unroll
            for (int n0 = 0; n0 < 8; n0++) { float v = facc[rt][n0][j]; s1 += v; s2 += v * v; }
#pragma unroll
            for (int d = 1; d < 16; d <<= 1) { s1 += __shfl_xor(s1, d); s2 += __shfl_xor(s2, d); }
            float m_ = s1 * (1.f / 128.f);
            mu[rt][j] = m_;
            rs[rt][j] = rsqrtf(s2 * (1.f / 128.f) - m_ * m_ + 1e-5f);
        }
#pragma unroll
    for (int n0 = 0; n0 < 8; n0++) {
        int c = n0 * 16 + lr;
        float g = ln2g[c], bb = ln2b[c];
#pragma unroll
        for (int rt = 0; rt < 2; rt++)
#pragma unroll
            for (int j = 0; j < 4; j++) {
                int row = R0 + rt * 16 + lg * 4 + j;
                out[(tok0 + row) * 128 + c] = (facc[rt][n0][j] - mu[rt][j]) * rs[rt][j] * g + bb;
            }
    }
}

extern "C" void kernel_launch(void* const* d_in, const int* in_sizes, int n_in,
                              void* d_out, int out_size, void* d_ws, size_t ws_size,
                              hipStream_t stream) {
    const float* x    = (const float*)d_in[0];
    const float* Wq   = (const float*)d_in[1];
    const float* Wk   = (const float*)d_in[2];
    const float* Wv   = (const float*)d_in[3];
    const float* Wo   = (const float*)d_in[4];
    const float* ln1g = (const float*)d_in[5];
    const float* ln1b = (const float*)d_in[6];
    const float* W1   = (const float*)d_in[7];
    const float* b1   = (const float*)d_in[8];
    const float* W2   = (const float*)d_in[9];
    const float* b2   = (const float*)d_in[10];
    const float* ln2g = (const float*)d_in[11];
    const float* ln2b = (const float*)d_in[12];
    float* out = (float*)d_out;

    // k1 grid: 1024 blocks (128 tok) if ws allows, else 512 (256 tok)
    const size_t fixed = (size_t)65536 * 2 /*KVt*/ + 2048 * 4 /*Ksf*/ +
                         4 * 16384 * 2 /*Wq,k,v,o t*/ + 65536 * 2 /*W1t*/ + 65536 * 2 /*W2t*/;
    const size_t need1024 = (size_t)1024 * 4096 * 2 + (size_t)1024 * 512 * 4 + fixed;
    int G, bpb_shift, nsub;
    if (ws_size >= need1024) { G = 1024; bpb_shift = 6; nsub = 2; }
    else                     { G = 512;  bpb_shift = 5; nsub = 4; }
    const int bpb = G >> 4;  // blocks per batch

    short* partKV = (short*)d_ws;                           // G*4*1024 bf16
    float* partKs = (float*)(partKV + (size_t)G * 4096);    // G*4*128  f32
    short* KVt    = (short*)(partKs + (size_t)G * 512);     // 64*1024  bf16 [m][d]
    float* Ksf    = (float*)(KVt + 65536);                  // 64*32    f32
    short* Wqt    = (short*)(Ksf + 2048);
    short* Wkt    = Wqt + 16384;
    short* Wvt    = Wkt + 16384;
    short* Wot    = Wvt + 16384;
    short* W1t    = Wot + 16384;                            // [512][128]
    short* W2t    = W1t + 65536;                            // [128][512]

    kw_conv<<<768, 256, 0, stream>>>(Wq, Wk, Wv, Wo, W1, W2, Wqt, Wkt, Wvt, Wot, W1t, W2t);
    k1_kv<<<G, 256, 0, stream>>>(x, Wkt, Wvt, partKV, partKs, bpb_shift, nsub);
    k2_red<<<64, 256, 0, stream>>>(partKV, partKs, KVt, Ksf, bpb);
    k3_main<<<1024, 256, 0, stream>>>(x, Wqt, Wot, KVt, Ksf, ln1g, ln1b, W1t, b1,
                                      W2t, b2, ln2g, ln2b, out);
}

// Round 4
// 368.699 us; speedup vs baseline: 1.3517x; 1.3517x over previous
//
#include <hip/hip_runtime.h>
#include <math.h>

// LinearAttentionBlock — bf16 MFMA v3.
// B=16, N=8192, D=128, H=4, dh=32, FF=512. mfma_f32_16x16x32_bf16.
// kw: weights -> bf16 [n][k].
// k1 (round-2 proven): staged x -> K=phi(x@Wk), V=x@Wv -> Kt/Vt LDS -> partial KV + Ksum.
// k2: reduce partials -> KVt bf16 [m][d], Ksum f32.
// k3: 64 tokens/block, wave-private (16 rows/wave), zero barriers, LDS 34.8KB,
//     low reg pressure -> 4 blocks/CU without spills.

using bfrag = __attribute__((ext_vector_type(8))) short;   // 8 bf16 (MFMA A/B)
using sh4   = __attribute__((ext_vector_type(4))) short;   // 4 bf16 (8B LDS write)
using ffrag = __attribute__((ext_vector_type(4))) float;   // MFMA C/D

#define MFMA(a, b, c) __builtin_amdgcn_mfma_f32_16x16x32_bf16((a), (b), (c), 0, 0, 0)

__device__ __forceinline__ float phi_fn(float v) { return v > 0.f ? v + 1.f : __expf(v); }

__device__ __forceinline__ short f2bf(float f) {
    union { float f; unsigned u; } v; v.f = f;
    unsigned r = v.u + 0x7fffu + ((v.u >> 16) & 1u);  // RNE
    return (short)(r >> 16);
}
__device__ __forceinline__ float bf2f(short s) {
    union { unsigned u; float f; } v; v.u = ((unsigned)(unsigned short)s) << 16;
    return v.f;
}

// ---------------- kw: weight convert + transpose ----------------
__global__ void kw_conv(const float* __restrict__ Wq, const float* __restrict__ Wk,
                        const float* __restrict__ Wv, const float* __restrict__ Wo,
                        const float* __restrict__ W1, const float* __restrict__ W2,
                        short* __restrict__ Wqt, short* __restrict__ Wkt,
                        short* __restrict__ Wvt, short* __restrict__ Wot,
                        short* __restrict__ W1t, short* __restrict__ W2t) {
    int i = blockIdx.x * 256 + threadIdx.x;
    if (i < 65536) {
        int mat = i >> 14, q = i & 16383, n = q >> 7, k = q & 127;
        const float* S = mat == 0 ? Wq : mat == 1 ? Wk : mat == 2 ? Wv : Wo;
        short* D = mat == 0 ? Wqt : mat == 1 ? Wkt : mat == 2 ? Wvt : Wot;
        D[n * 128 + k] = f2bf(S[k * 128 + n]);
    } else if (i < 131072) {
        int q = i - 65536, n = q >> 7, k = q & 127;
        W1t[n * 128 + k] = f2bf(W1[k * 512 + n]);
    } else {
        int q = i - 131072, n = q >> 9, k = q & 511;
        W2t[n * 512 + k] = f2bf(W2[k * 128 + n]);
    }
}

// ---------------- k1: K/V proj + partial KV (round-2 proven) ----------------
// 512 blocks x 256 thr; 256 tokens/block (4 subtiles of 64); wave w = head w.
__global__ __launch_bounds__(256, 2) void k1_kv(
    const float* __restrict__ x, const short* __restrict__ Wkt,
    const short* __restrict__ Wvt, short* __restrict__ partKV,
    float* __restrict__ partKs) {
    __shared__ short sx[64][136];
    __shared__ short Kt[128][72];  // [dim][token]
    __shared__ short Vt[128][72];

    const int t = threadIdx.x, w = t >> 6, l = t & 63, lr = l & 15, lg = l >> 4;
    const int blk = blockIdx.x, b = blk >> 5;
    const size_t tok0 = ((size_t)b << 13) + (size_t)(blk & 31) * 256;

    ffrag kvacc[2][2];
#pragma unroll
    for (int dt = 0; dt < 2; dt++)
#pragma unroll
        for (int mt = 0; mt < 2; mt++) kvacc[dt][mt] = ffrag{0.f, 0.f, 0.f, 0.f};
    float accKs[8];
#pragma unroll
    for (int i = 0; i < 8; i++) accKs[i] = 0.f;

    for (int s = 0; s < 4; ++s) {
        // stage own 16 rows (wave-private)
        const float* xb = x + (tok0 + (size_t)s * 64 + w * 16) * 128;
#pragma unroll
        for (int it = 0; it < 4; ++it) {
            int idx = it * 64 + l;  // 0..255
            int row = idx >> 4, c8 = (idx & 15) * 8;
            const float4* p = (const float4*)(xb + row * 128 + c8);
            float4 v0 = p[0], v1 = p[1];
            bfrag sv;
            sv[0] = f2bf(v0.x); sv[1] = f2bf(v0.y); sv[2] = f2bf(v0.z); sv[3] = f2bf(v0.w);
            sv[4] = f2bf(v1.x); sv[5] = f2bf(v1.y); sv[6] = f2bf(v1.z); sv[7] = f2bf(v1.w);
            *(bfrag*)&sx[w * 16 + row][c8] = sv;
        }
        bfrag xf[4];
#pragma unroll
        for (int kk = 0; kk < 4; kk++)
            xf[kk] = *(const bfrag*)&sx[w * 16 + lr][kk * 32 + lg * 8];
        const int toff = w * 16 + lg * 4;
#pragma unroll
        for (int n0 = 0; n0 < 8; n0++) {
            ffrag ck = {0.f, 0.f, 0.f, 0.f}, cv = {0.f, 0.f, 0.f, 0.f};
#pragma unroll
            for (int kk = 0; kk < 4; kk++) {
                bfrag bk = *(const bfrag*)(Wkt + (n0 * 16 + lr) * 128 + kk * 32 + lg * 8);
                bfrag bv = *(const bfrag*)(Wvt + (n0 * 16 + lr) * 128 + kk * 32 + lg * 8);
                ck = MFMA(xf[kk], bk, ck);
                cv = MFMA(xf[kk], bv, cv);
            }
            sh4 ks, vs;
#pragma unroll
            for (int j = 0; j < 4; j++) {
                float pv = phi_fn(ck[j]);
                accKs[n0] += pv;
                ks[j] = f2bf(pv);
                vs[j] = f2bf(cv[j]);
            }
            *(sh4*)&Kt[n0 * 16 + lr][toff] = ks;
            *(sh4*)&Vt[n0 * 16 + lr][toff] = vs;
        }
        __syncthreads();
        // KV accumulate over 64 tokens: A=Kt rows (head-w dims), B=Vt rows
#pragma unroll
        for (int kk = 0; kk < 2; kk++) {
            bfrag ka0 = *(const bfrag*)&Kt[w * 32 + lr][kk * 32 + lg * 8];
            bfrag ka1 = *(const bfrag*)&Kt[w * 32 + 16 + lr][kk * 32 + lg * 8];
            bfrag vb0 = *(const bfrag*)&Vt[w * 32 + lr][kk * 32 + lg * 8];
            bfrag vb1 = *(const bfrag*)&Vt[w * 32 + 16 + lr][kk * 32 + lg * 8];
            kvacc[0][0] = MFMA(ka0, vb0, kvacc[0][0]);
            kvacc[0][1] = MFMA(ka0, vb1, kvacc[0][1]);
            kvacc[1][0] = MFMA(ka1, vb0, kvacc[1][0]);
            kvacc[1][1] = MFMA(ka1, vb1, kvacc[1][1]);
        }
        __syncthreads();
    }
    short* pk = partKV + ((size_t)(blk * 4 + w) << 10);
#pragma unroll
    for (int dt = 0; dt < 2; dt++)
#pragma unroll
        for (int mt = 0; mt < 2; mt++)
#pragma unroll
            for (int j = 0; j < 4; j++)
                pk[(dt * 16 + lg * 4 + j) * 32 + mt * 16 + lr] = f2bf(kvacc[dt][mt][j]);
#pragma unroll
    for (int n0 = 0; n0 < 8; n0++) {
        float v = accKs[n0];
        v += __shfl_xor(v, 16);
        v += __shfl_xor(v, 32);
        if (l < 16) partKs[(blk * 4 + w) * 128 + n0 * 16 + l] = v;
    }
}

// ---------------- k2: reduce partials ----------------
__global__ void k2_red(const short* __restrict__ partKV, const float* __restrict__ partKs,
                       short* __restrict__ KVt, float* __restrict__ Ksf) {
    int bh = blockIdx.x, b = bh >> 2, h = bh & 3, t = threadIdx.x;
    for (int idx = t; idx < 1024; idx += 256) {
        int d = idx >> 5, m = idx & 31;
        float s = 0.f;
        for (int i = 0; i < 32; i++)
            s += bf2f(partKV[((size_t)((b * 32 + i) * 4 + h) << 10) + idx]);
        KVt[((size_t)bh << 10) + m * 32 + d] = f2bf(s);  // transposed [m][d]
    }
    if (t < 32) {
        float s = 0.f;
        for (int i = 0; i < 32; i++)
            for (int w = 0; w < 4; w++)
                s += partKs[((b * 32 + i) * 4 + w) * 128 + h * 32 + t];
        Ksf[bh * 32 + t] = s;
    }
}

// ---------------- k3: fused main (zero barriers; 16 rows/wave; 34.8KB LDS) ----------------
// 2048 blocks x 256 thr; 64 tokens/block; wave w owns rows 16w..16w+15.
__global__ __launch_bounds__(256, 4) void k3_main(
    const float* __restrict__ x, const short* __restrict__ Wqt,
    const short* __restrict__ Wot, const short* __restrict__ KVt,
    const float* __restrict__ Ksf, const float* __restrict__ ln1g,
    const float* __restrict__ ln1b, const short* __restrict__ W1t,
    const float* __restrict__ b1, const short* __restrict__ W2t,
    const float* __restrict__ b2, const float* __restrict__ ln2g,
    const float* __restrict__ ln2b, float* __restrict__ out) {
    __shared__ short sbuf[64][136];  // x -> Q -> attn -> h chunks
    __shared__ short ybuf[64][136];  // y (LN1 out)

    const int t = threadIdx.x, w = t >> 6, l = t & 63, lr = l & 15, lg = l >> 4;
    const int blk = blockIdx.x, b = blk >> 7;
    const size_t tok0 = ((size_t)b << 13) + (size_t)(blk & 127) * 64;
    const int R0 = w * 16;

    // ---- stage own 16 rows of x as bf16 (coalesced float4) ----
    const float* xw = x + (tok0 + R0) * 128;
#pragma unroll
    for (int it = 0; it < 4; ++it) {
        int idx = it * 64 + l;  // 0..255
        int row = idx >> 4, c8 = (idx & 15) * 8;
        const float4* p = (const float4*)(xw + row * 128 + c8);
        float4 v0 = p[0], v1 = p[1];
        bfrag sv;
        sv[0] = f2bf(v0.x); sv[1] = f2bf(v0.y); sv[2] = f2bf(v0.z); sv[3] = f2bf(v0.w);
        sv[4] = f2bf(v1.x); sv[5] = f2bf(v1.y); sv[6] = f2bf(v1.z); sv[7] = f2bf(v1.w);
        *(bfrag*)&sbuf[R0 + row][c8] = sv;
    }

    // ---- Q = phi(x@Wq), in place over x ----
    bfrag xf[4];
#pragma unroll
    for (int kk = 0; kk < 4; kk++)
        xf[kk] = *(const bfrag*)&sbuf[R0 + lr][kk * 32 + lg * 8];
#pragma unroll
    for (int n0 = 0; n0 < 8; n0++) {
        ffrag c0 = {0.f, 0.f, 0.f, 0.f};
#pragma unroll
        for (int kk = 0; kk < 4; kk++) {
            bfrag bw = *(const bfrag*)(Wqt + (n0 * 16 + lr) * 128 + kk * 32 + lg * 8);
            c0 = MFMA(xf[kk], bw, c0);
        }
#pragma unroll
        for (int j = 0; j < 4; j++)
            sbuf[R0 + lg * 4 + j][n0 * 16 + lr] = f2bf(phi_fn(c0[j]));
    }

    // ---- attn per head: denom (shfl broadcast) + Q@KV, in place over Q ----
#pragma unroll
    for (int h = 0; h < 4; h++) {
        bfrag qf = *(const bfrag*)&sbuf[R0 + lr][h * 32 + lg * 8];
        const float4* kp = (const float4*)(Ksf + (b * 4 + h) * 32 + lg * 8);
        float4 ka = kp[0], kb = kp[1];
        float ksv[8] = {ka.x, ka.y, ka.z, ka.w, kb.x, kb.y, kb.z, kb.w};
        float p0 = 0.f;
#pragma unroll
        for (int j = 0; j < 8; j++) p0 += bf2f(qf[j]) * ksv[j];
        p0 += __shfl_xor(p0, 16);
        p0 += __shfl_xor(p0, 32);
        float den0 = fmaxf(p0, 1e-6f);  // denom for row R0+lr, in all lanes
        const ffrag fz = {0.f, 0.f, 0.f, 0.f};
#pragma unroll
        for (int mt = 0; mt < 2; mt++) {
            bfrag bkv = *(const bfrag*)(KVt + ((size_t)(b * 4 + h) << 10) + (mt * 16 + lr) * 32 + lg * 8);
            ffrag c0 = MFMA(qf, bkv, fz);
#pragma unroll
            for (int j = 0; j < 4; j++) {
                float dv = __shfl(den0, lg * 4 + j);  // denom of row R0+lg*4+j
                sbuf[R0 + lg * 4 + j][h * 32 + mt * 16 + lr] = f2bf(c0[j] / dv);
            }
        }
    }

    // ---- Wo + residual (f32 x re-read) + LN1 ----
    bfrag af[4];
#pragma unroll
    for (int kk = 0; kk < 4; kk++)
        af[kk] = *(const bfrag*)&sbuf[R0 + lr][kk * 32 + lg * 8];
    float r[8][4];
#pragma unroll
    for (int n0 = 0; n0 < 8; n0++) {
        ffrag c0 = {0.f, 0.f, 0.f, 0.f};
#pragma unroll
        for (int kk = 0; kk < 4; kk++) {
            bfrag bw = *(const bfrag*)(Wot + (n0 * 16 + lr) * 128 + kk * 32 + lg * 8);
            c0 = MFMA(af[kk], bw, c0);
        }
#pragma unroll
        for (int j = 0; j < 4; j++)
            r[n0][j] = c0[j] + x[(tok0 + R0 + lg * 4 + j) * 128 + n0 * 16 + lr];
    }
    float mu[4], rs[4];
#pragma unroll
    for (int j = 0; j < 4; j++) {
        float s1 = 0.f, s2 = 0.f;
#pragma unroll
        for (int n0 = 0; n0 < 8; n0++) { float v = r[n0][j]; s1 += v; s2 += v * v; }
#pragma unroll
        for (int d = 1; d < 16; d <<= 1) { s1 += __shfl_xor(s1, d); s2 += __shfl_xor(s2, d); }
        float m_ = s1 * (1.f / 128.f);
        mu[j] = m_;
        rs[j] = rsqrtf(s2 * (1.f / 128.f) - m_ * m_ + 1e-5f);
    }
#pragma unroll
    for (int n0 = 0; n0 < 8; n0++) {
        int c = n0 * 16 + lr;
        float g = ln1g[c], bb = ln1b[c];
#pragma unroll
        for (int j = 0; j < 4; j++)
            ybuf[R0 + lg * 4 + j][c] = f2bf((r[n0][j] - mu[j]) * rs[j] * g + bb);
    }

    // ---- FF: h = relu(y@W1+b1) (4 chunks), f = h@W2 accumulated ----
    bfrag yf[4];
#pragma unroll
    for (int kk = 0; kk < 4; kk++)
        yf[kk] = *(const bfrag*)&ybuf[R0 + lr][kk * 32 + lg * 8];
    ffrag facc[8];
#pragma unroll
    for (int n0 = 0; n0 < 8; n0++) facc[n0] = ffrag{0.f, 0.f, 0.f, 0.f};
    for (int ch = 0; ch < 4; ++ch) {
#pragma unroll
        for (int n0 = 0; n0 < 8; n0++) {
            ffrag c0 = {0.f, 0.f, 0.f, 0.f};
#pragma unroll
            for (int kk = 0; kk < 4; kk++) {
                bfrag bw = *(const bfrag*)(W1t + (ch * 128 + n0 * 16 + lr) * 128 + kk * 32 + lg * 8);
                c0 = MFMA(yf[kk], bw, c0);
            }
            float bb = b1[ch * 128 + n0 * 16 + lr];
#pragma unroll
            for (int j = 0; j < 4; j++)
                sbuf[R0 + lg * 4 + j][n0 * 16 + lr] = f2bf(fmaxf(c0[j] + bb, 0.f));
        }
        bfrag hf[4];
#pragma unroll
        for (int kk = 0; kk < 4; kk++)
            hf[kk] = *(const bfrag*)&sbuf[R0 + lr][kk * 32 + lg * 8];
#pragma unroll
        for (int n0 = 0; n0 < 8; n0++) {
#pragma unroll
            for (int kk = 0; kk < 4; kk++) {
                bfrag bw = *(const bfrag*)(W2t + (n0 * 16 + lr) * 512 + ch * 128 + kk * 32 + lg * 8);
                facc[n0] = MFMA(hf[kk], bw, facc[n0]);
            }
        }
    }

    // ---- residual2 (y bf16 from ybuf) + LN2 + store ----
#pragma unroll
    for (int n0 = 0; n0 < 8; n0++) {
        int c = n0 * 16 + lr;
        float bb = b2[c];
#pragma unroll
        for (int j = 0; j < 4; j++)
            facc[n0][j] = facc[n0][j] + bf2f(ybuf[R0 + lg * 4 + j][c]) + bb;
    }
#pragma unroll
    for (int j = 0; j < 4; j++) {
        float s1 = 0.f, s2 = 0.f;
#pragma unroll
        for (int n0 = 0; n0 < 8; n0++) { float v = facc[n0][j]; s1 += v; s2 += v * v; }
#pragma unroll
        for (int d = 1; d < 16; d <<= 1) { s1 += __shfl_xor(s1, d); s2 += __shfl_xor(s2, d); }
        float m_ = s1 * (1.f / 128.f);
        mu[j] = m_;
        rs[j] = rsqrtf(s2 * (1.f / 128.f) - m_ * m_ + 1e-5f);
    }
#pragma unroll
    for (int n0 = 0; n0 < 8; n0++) {
        int c = n0 * 16 + lr;
        float g = ln2g[c], bb = ln2b[c];
#pragma unroll
        for (int j = 0; j < 4; j++) {
            int row = R0 + lg * 4 + j;
            out[(tok0 + row) * 128 + c] = (facc[n0][j] - mu[j]) * rs[j] * g + bb;
        }
    }
}

extern "C" void kernel_launch(void* const* d_in, const int* in_sizes, int n_in,
                              void* d_out, int out_size, void* d_ws, size_t ws_size,
                              hipStream_t stream) {
    const float* x    = (const float*)d_in[0];
    const float* Wq   = (const float*)d_in[1];
    const float* Wk   = (const float*)d_in[2];
    const float* Wv   = (const float*)d_in[3];
    const float* Wo   = (const float*)d_in[4];
    const float* ln1g = (const float*)d_in[5];
    const float* ln1b = (const float*)d_in[6];
    const float* W1   = (const float*)d_in[7];
    const float* b1   = (const float*)d_in[8];
    const float* W2   = (const float*)d_in[9];
    const float* b2   = (const float*)d_in[10];
    const float* ln2g = (const float*)d_in[11];
    const float* ln2b = (const float*)d_in[12];
    float* out = (float*)d_out;

    // ws layout (~5.7 MB)
    short* partKV = (short*)d_ws;                       // 512*4*1024 bf16
    float* partKs = (float*)(partKV + 2097152);         // 512*4*128  f32
    short* KVt    = (short*)(partKs + 262144);          // 64*1024    bf16 [m][d]
    float* Ksf    = (float*)(KVt + 65536);              // 64*32      f32
    short* Wqt    = (short*)(Ksf + 2048);
    short* Wkt    = Wqt + 16384;
    short* Wvt    = Wkt + 16384;
    short* Wot    = Wvt + 16384;
    short* W1t    = Wot + 16384;                        // [512][128]
    short* W2t    = W1t + 65536;                        // [128][512]

    kw_conv<<<768, 256, 0, stream>>>(Wq, Wk, Wv, Wo, W1, W2, Wqt, Wkt, Wvt, Wot, W1t, W2t);
    k1_kv<<<512, 256, 0, stream>>>(x, Wkt, Wvt, partKV, partKs);
    k2_red<<<64, 256, 0, stream>>>(partKV, partKs, KVt, Ksf);
    k3_main<<<2048, 256, 0, stream>>>(x, Wqt, Wot, KVt, Ksf, ln1g, ln1b, W1t, b1,
                                      W2t, b2, ln2g, ln2b, out);
}

// Round 5
// 246.670 us; speedup vs baseline: 2.0204x; 1.4947x over previous
//
#include <hip/hip_runtime.h>
#include <math.h>

// LinearAttentionBlock — bf16 MFMA v4 (round-2 structure + latency-chain cuts).
// B=16, N=8192, D=128, H=4, dh=32, FF=512. mfma_f32_16x16x32_bf16.
// kw: weights -> bf16 [n][k].
// k1: staged x (prefetched) -> K=phi(x@Wk), V=x@Wv -> Kt/Vt LDS -> partial KV + Ksum.
// k2: reduce partials -> KVt bf16 [m][d], Ksum f32.
// k3: wave-private fused (32 rows/wave, zero barriers), weight prefetch,
//     residual x from LDS bf16 copy, rcp instead of div.

using bfrag = __attribute__((ext_vector_type(8))) short;   // 8 bf16 (MFMA A/B)
using sh4   = __attribute__((ext_vector_type(4))) short;   // 4 bf16 (8B LDS write)
using ffrag = __attribute__((ext_vector_type(4))) float;   // MFMA C/D

#define MFMA(a, b, c) __builtin_amdgcn_mfma_f32_16x16x32_bf16((a), (b), (c), 0, 0, 0)

__device__ __forceinline__ float phi_fn(float v) { return v > 0.f ? v + 1.f : __expf(v); }

__device__ __forceinline__ short f2bf(float f) {
    union { float f; unsigned u; } v; v.f = f;
    unsigned r = v.u + 0x7fffu + ((v.u >> 16) & 1u);  // RNE
    return (short)(r >> 16);
}
__device__ __forceinline__ float bf2f(short s) {
    union { unsigned u; float f; } v; v.u = ((unsigned)(unsigned short)s) << 16;
    return v.f;
}

// ---------------- kw: weight convert + transpose ----------------
__global__ void kw_conv(const float* __restrict__ Wq, const float* __restrict__ Wk,
                        const float* __restrict__ Wv, const float* __restrict__ Wo,
                        const float* __restrict__ W1, const float* __restrict__ W2,
                        short* __restrict__ Wqt, short* __restrict__ Wkt,
                        short* __restrict__ Wvt, short* __restrict__ Wot,
                        short* __restrict__ W1t, short* __restrict__ W2t) {
    int i = blockIdx.x * 256 + threadIdx.x;
    if (i < 65536) {
        int mat = i >> 14, q = i & 16383, n = q >> 7, k = q & 127;
        const float* S = mat == 0 ? Wq : mat == 1 ? Wk : mat == 2 ? Wv : Wo;
        short* D = mat == 0 ? Wqt : mat == 1 ? Wkt : mat == 2 ? Wvt : Wot;
        D[n * 128 + k] = f2bf(S[k * 128 + n]);
    } else if (i < 131072) {
        int q = i - 65536, n = q >> 7, k = q & 127;
        W1t[n * 128 + k] = f2bf(W1[k * 512 + n]);
    } else {
        int q = i - 131072, n = q >> 9, k = q & 511;
        W2t[n * 512 + k] = f2bf(W2[k * 128 + n]);
    }
}

// ---------------- k1: K/V proj + partial KV ----------------
// 512 blocks x 256 thr; 256 tokens/block (4 subtiles of 64); wave w = head w.
__global__ __launch_bounds__(256, 2) void k1_kv(
    const float* __restrict__ x, const short* __restrict__ Wkt,
    const short* __restrict__ Wvt, short* __restrict__ partKV,
    float* __restrict__ partKs) {
    __shared__ short sx[64][136];
    __shared__ short Kt[128][72];  // [dim][token]
    __shared__ short Vt[128][72];

    const int t = threadIdx.x, w = t >> 6, l = t & 63, lr = l & 15, lg = l >> 4;
    const int blk = blockIdx.x, b = blk >> 5;
    const size_t tok0 = ((size_t)b << 13) + (size_t)(blk & 31) * 256;

    ffrag kvacc[2][2];
#pragma unroll
    for (int dt = 0; dt < 2; dt++)
#pragma unroll
        for (int mt = 0; mt < 2; mt++) kvacc[dt][mt] = ffrag{0.f, 0.f, 0.f, 0.f};
    float accKs[8];
#pragma unroll
    for (int i = 0; i < 8; i++) accKs[i] = 0.f;

    // prologue: prefetch subtile 0
    float4 pv0[4], pv1[4];
    {
        const float* xb = x + (tok0 + (size_t)w * 16) * 128;
#pragma unroll
        for (int it = 0; it < 4; ++it) {
            int idx = it * 64 + l, row = idx >> 4, c8 = (idx & 15) * 8;
            const float4* p = (const float4*)(xb + row * 128 + c8);
            pv0[it] = p[0]; pv1[it] = p[1];
        }
    }

    for (int s = 0; s < 4; ++s) {
        // write prefetched x subtile to LDS (wave-private rows)
#pragma unroll
        for (int it = 0; it < 4; ++it) {
            int idx = it * 64 + l, row = idx >> 4, c8 = (idx & 15) * 8;
            bfrag sv;
            sv[0] = f2bf(pv0[it].x); sv[1] = f2bf(pv0[it].y);
            sv[2] = f2bf(pv0[it].z); sv[3] = f2bf(pv0[it].w);
            sv[4] = f2bf(pv1[it].x); sv[5] = f2bf(pv1[it].y);
            sv[6] = f2bf(pv1[it].z); sv[7] = f2bf(pv1[it].w);
            *(bfrag*)&sx[w * 16 + row][c8] = sv;
        }
        bfrag xf[4];
#pragma unroll
        for (int kk = 0; kk < 4; kk++)
            xf[kk] = *(const bfrag*)&sx[w * 16 + lr][kk * 32 + lg * 8];
        // prefetch next subtile's globals (overlaps GEMM below)
        if (s < 3) {
            const float* xb = x + (tok0 + (size_t)(s + 1) * 64 + w * 16) * 128;
#pragma unroll
            for (int it = 0; it < 4; ++it) {
                int idx = it * 64 + l, row = idx >> 4, c8 = (idx & 15) * 8;
                const float4* p = (const float4*)(xb + row * 128 + c8);
                pv0[it] = p[0]; pv1[it] = p[1];
            }
        }
        const int toff = w * 16 + lg * 4;
        // K/V GEMM with next-n0 weight prefetch
        bfrag bk[4], bv[4], bkn[4], bvn[4];
#pragma unroll
        for (int kk = 0; kk < 4; kk++) {
            bk[kk] = *(const bfrag*)(Wkt + lr * 128 + kk * 32 + lg * 8);
            bv[kk] = *(const bfrag*)(Wvt + lr * 128 + kk * 32 + lg * 8);
        }
#pragma unroll
        for (int n0 = 0; n0 < 8; n0++) {
            if (n0 < 7) {
#pragma unroll
                for (int kk = 0; kk < 4; kk++) {
                    bkn[kk] = *(const bfrag*)(Wkt + ((n0 + 1) * 16 + lr) * 128 + kk * 32 + lg * 8);
                    bvn[kk] = *(const bfrag*)(Wvt + ((n0 + 1) * 16 + lr) * 128 + kk * 32 + lg * 8);
                }
            }
            ffrag ck = {0.f, 0.f, 0.f, 0.f}, cv = {0.f, 0.f, 0.f, 0.f};
#pragma unroll
            for (int kk = 0; kk < 4; kk++) {
                ck = MFMA(xf[kk], bk[kk], ck);
                cv = MFMA(xf[kk], bv[kk], cv);
            }
            sh4 ks, vs;
#pragma unroll
            for (int j = 0; j < 4; j++) {
                float pvf = phi_fn(ck[j]);
                accKs[n0] += pvf;
                ks[j] = f2bf(pvf);
                vs[j] = f2bf(cv[j]);
            }
            *(sh4*)&Kt[n0 * 16 + lr][toff] = ks;
            *(sh4*)&Vt[n0 * 16 + lr][toff] = vs;
            if (n0 < 7) {
#pragma unroll
                for (int kk = 0; kk < 4; kk++) { bk[kk] = bkn[kk]; bv[kk] = bvn[kk]; }
            }
        }
        __syncthreads();
        // KV accumulate over 64 tokens: A=Kt rows (head-w dims), B=Vt rows
#pragma unroll
        for (int kk = 0; kk < 2; kk++) {
            bfrag ka0 = *(const bfrag*)&Kt[w * 32 + lr][kk * 32 + lg * 8];
            bfrag ka1 = *(const bfrag*)&Kt[w * 32 + 16 + lr][kk * 32 + lg * 8];
            bfrag vb0 = *(const bfrag*)&Vt[w * 32 + lr][kk * 32 + lg * 8];
            bfrag vb1 = *(const bfrag*)&Vt[w * 32 + 16 + lr][kk * 32 + lg * 8];
            kvacc[0][0] = MFMA(ka0, vb0, kvacc[0][0]);
            kvacc[0][1] = MFMA(ka0, vb1, kvacc[0][1]);
            kvacc[1][0] = MFMA(ka1, vb0, kvacc[1][0]);
            kvacc[1][1] = MFMA(ka1, vb1, kvacc[1][1]);
        }
        __syncthreads();
    }
    short* pk = partKV + ((size_t)(blk * 4 + w) << 10);
#pragma unroll
    for (int dt = 0; dt < 2; dt++)
#pragma unroll
        for (int mt = 0; mt < 2; mt++)
#pragma unroll
            for (int j = 0; j < 4; j++)
                pk[(dt * 16 + lg * 4 + j) * 32 + mt * 16 + lr] = f2bf(kvacc[dt][mt][j]);
#pragma unroll
    for (int n0 = 0; n0 < 8; n0++) {
        float v = accKs[n0];
        v += __shfl_xor(v, 16);
        v += __shfl_xor(v, 32);
        if (l < 16) partKs[(blk * 4 + w) * 128 + n0 * 16 + l] = v;
    }
}

// ---------------- k2: reduce partials ----------------
__global__ void k2_red(const short* __restrict__ partKV, const float* __restrict__ partKs,
                       short* __restrict__ KVt, float* __restrict__ Ksf) {
    int bh = blockIdx.x, b = bh >> 2, h = bh & 3, t = threadIdx.x;
    for (int idx = t; idx < 1024; idx += 256) {
        int d = idx >> 5, m = idx & 31;
        float s = 0.f;
        for (int i = 0; i < 32; i++)
            s += bf2f(partKV[((size_t)((b * 32 + i) * 4 + h) << 10) + idx]);
        KVt[((size_t)bh << 10) + m * 32 + d] = f2bf(s);  // transposed [m][d]
    }
    if (t < 32) {
        float s = 0.f;
        for (int i = 0; i < 32; i++)
            for (int w = 0; w < 4; w++)
                s += partKs[((b * 32 + i) * 4 + w) * 128 + h * 32 + t];
        Ksf[bh * 32 + t] = s;
    }
}

// ---------------- k3: fused main (zero barriers; wave-private 32 rows) ----------------
// 1024 blocks x 256 thr; 128 tokens/block; wave w owns rows 32w..32w+31.
__global__ __launch_bounds__(256, 2) void k3_main(
    const float* __restrict__ x, const short* __restrict__ Wqt,
    const short* __restrict__ Wot, const short* __restrict__ KVt,
    const float* __restrict__ Ksf, const float* __restrict__ ln1g,
    const float* __restrict__ ln1b, const short* __restrict__ W1t,
    const float* __restrict__ b1, const short* __restrict__ W2t,
    const float* __restrict__ b2, const float* __restrict__ ln2g,
    const float* __restrict__ ln2b, float* __restrict__ out) {
    __shared__ short sbuf[128][136];  // x -> Q -> attn -> h chunks
    __shared__ short ybuf[128][136];  // x copy (residual) -> y (LN1 out)

    const int t = threadIdx.x, w = t >> 6, l = t & 63, lr = l & 15, lg = l >> 4;
    const int blk = blockIdx.x, b = blk >> 6;
    const size_t tok0 = ((size_t)b << 13) + (size_t)(blk & 63) * 128;
    const int R0 = w * 32;
    const float* xw = x + (tok0 + R0) * 128;

    // ---- stage own 32 rows of x as bf16 into sbuf AND ybuf ----
#pragma unroll
    for (int it = 0; it < 8; ++it) {
        int idx = it * 64 + l, row = idx >> 4, c8 = (idx & 15) * 8;
        const float4* p = (const float4*)(xw + row * 128 + c8);
        float4 v0 = p[0], v1 = p[1];
        bfrag sv;
        sv[0] = f2bf(v0.x); sv[1] = f2bf(v0.y); sv[2] = f2bf(v0.z); sv[3] = f2bf(v0.w);
        sv[4] = f2bf(v1.x); sv[5] = f2bf(v1.y); sv[6] = f2bf(v1.z); sv[7] = f2bf(v1.w);
        *(bfrag*)&sbuf[R0 + row][c8] = sv;
        *(bfrag*)&ybuf[R0 + row][c8] = sv;
    }

    // ---- Q = phi(x@Wq), in place over x (weight prefetch) ----
    bfrag xf[2][4];
#pragma unroll
    for (int rt = 0; rt < 2; rt++)
#pragma unroll
        for (int kk = 0; kk < 4; kk++)
            xf[rt][kk] = *(const bfrag*)&sbuf[R0 + rt * 16 + lr][kk * 32 + lg * 8];
    {
        bfrag bw[4], bwn[4];
#pragma unroll
        for (int kk = 0; kk < 4; kk++)
            bw[kk] = *(const bfrag*)(Wqt + lr * 128 + kk * 32 + lg * 8);
#pragma unroll
        for (int n0 = 0; n0 < 8; n0++) {
            if (n0 < 7) {
#pragma unroll
                for (int kk = 0; kk < 4; kk++)
                    bwn[kk] = *(const bfrag*)(Wqt + ((n0 + 1) * 16 + lr) * 128 + kk * 32 + lg * 8);
            }
            ffrag c0 = {0.f, 0.f, 0.f, 0.f}, c1 = {0.f, 0.f, 0.f, 0.f};
#pragma unroll
            for (int kk = 0; kk < 4; kk++) {
                c0 = MFMA(xf[0][kk], bw[kk], c0);
                c1 = MFMA(xf[1][kk], bw[kk], c1);
            }
#pragma unroll
            for (int j = 0; j < 4; j++) {
                sbuf[R0 + lg * 4 + j][n0 * 16 + lr] = f2bf(phi_fn(c0[j]));
                sbuf[R0 + 16 + lg * 4 + j][n0 * 16 + lr] = f2bf(phi_fn(c1[j]));
            }
            if (n0 < 7) {
#pragma unroll
                for (int kk = 0; kk < 4; kk++) bw[kk] = bwn[kk];
            }
        }
    }

    // ---- attn per head: denom (shfl) -> rcp -> Q@KV, in place over Q ----
#pragma unroll
    for (int h = 0; h < 4; h++) {
        bfrag qf0 = *(const bfrag*)&sbuf[R0 + lr][h * 32 + lg * 8];
        bfrag qf1 = *(const bfrag*)&sbuf[R0 + 16 + lr][h * 32 + lg * 8];
        const float4* kp = (const float4*)(Ksf + (b * 4 + h) * 32 + lg * 8);
        float4 ka = kp[0], kb = kp[1];
        float ksv[8] = {ka.x, ka.y, ka.z, ka.w, kb.x, kb.y, kb.z, kb.w};
        float p0 = 0.f, p1 = 0.f;
#pragma unroll
        for (int j = 0; j < 8; j++) {
            p0 += bf2f(qf0[j]) * ksv[j];
            p1 += bf2f(qf1[j]) * ksv[j];
        }
        p0 += __shfl_xor(p0, 16); p0 += __shfl_xor(p0, 32);
        p1 += __shfl_xor(p1, 16); p1 += __shfl_xor(p1, 32);
        float rd0 = __builtin_amdgcn_rcpf(fmaxf(p0, 1e-6f));
        float rd1 = __builtin_amdgcn_rcpf(fmaxf(p1, 1e-6f));
        float dv0[4], dv1[4];
#pragma unroll
        for (int j = 0; j < 4; j++) {
            dv0[j] = __shfl(rd0, lg * 4 + j);
            dv1[j] = __shfl(rd1, lg * 4 + j);
        }
        const ffrag fz = {0.f, 0.f, 0.f, 0.f};
#pragma unroll
        for (int mt = 0; mt < 2; mt++) {
            bfrag bkv = *(const bfrag*)(KVt + ((size_t)(b * 4 + h) << 10) + (mt * 16 + lr) * 32 + lg * 8);
            ffrag c0 = MFMA(qf0, bkv, fz);
            ffrag c1 = MFMA(qf1, bkv, fz);
#pragma unroll
            for (int j = 0; j < 4; j++) {
                sbuf[R0 + lg * 4 + j][h * 32 + mt * 16 + lr] = f2bf(c0[j] * dv0[j]);
                sbuf[R0 + 16 + lg * 4 + j][h * 32 + mt * 16 + lr] = f2bf(c1[j] * dv1[j]);
            }
        }
    }

    // ---- Wo (prefetch) + residual (bf16 x from ybuf) + LN1 ----
    bfrag af[2][4];
#pragma unroll
    for (int rt = 0; rt < 2; rt++)
#pragma unroll
        for (int kk = 0; kk < 4; kk++)
            af[rt][kk] = *(const bfrag*)&sbuf[R0 + rt * 16 + lr][kk * 32 + lg * 8];
    float r[2][8][4];
    {
        bfrag bw[4], bwn[4];
#pragma unroll
        for (int kk = 0; kk < 4; kk++)
            bw[kk] = *(const bfrag*)(Wot + lr * 128 + kk * 32 + lg * 8);
#pragma unroll
        for (int n0 = 0; n0 < 8; n0++) {
            if (n0 < 7) {
#pragma unroll
                for (int kk = 0; kk < 4; kk++)
                    bwn[kk] = *(const bfrag*)(Wot + ((n0 + 1) * 16 + lr) * 128 + kk * 32 + lg * 8);
            }
            ffrag c0 = {0.f, 0.f, 0.f, 0.f}, c1 = {0.f, 0.f, 0.f, 0.f};
#pragma unroll
            for (int kk = 0; kk < 4; kk++) {
                c0 = MFMA(af[0][kk], bw[kk], c0);
                c1 = MFMA(af[1][kk], bw[kk], c1);
            }
#pragma unroll
            for (int j = 0; j < 4; j++) {
                r[0][n0][j] = c0[j] + bf2f(ybuf[R0 + lg * 4 + j][n0 * 16 + lr]);
                r[1][n0][j] = c1[j] + bf2f(ybuf[R0 + 16 + lg * 4 + j][n0 * 16 + lr]);
            }
            if (n0 < 7) {
#pragma unroll
                for (int kk = 0; kk < 4; kk++) bw[kk] = bwn[kk];
            }
        }
    }
    float mu[2][4], rs[2][4];
#pragma unroll
    for (int rt = 0; rt < 2; rt++)
#pragma unroll
        for (int j = 0; j < 4; j++) {
            float s1 = 0.f, s2 = 0.f;
#pragma unroll
            for (int n0 = 0; n0 < 8; n0++) { float v = r[rt][n0][j]; s1 += v; s2 += v * v; }
#pragma unroll
            for (int d = 1; d < 16; d <<= 1) { s1 += __shfl_xor(s1, d); s2 += __shfl_xor(s2, d); }
            float m_ = s1 * (1.f / 128.f);
            mu[rt][j] = m_;
            rs[rt][j] = rsqrtf(s2 * (1.f / 128.f) - m_ * m_ + 1e-5f);
        }
    // y -> ybuf (overwrites x copy after residual reads; wave-private order)
#pragma unroll
    for (int n0 = 0; n0 < 8; n0++) {
        int c = n0 * 16 + lr;
        float g = ln1g[c], bb = ln1b[c];
#pragma unroll
        for (int rt = 0; rt < 2; rt++)
#pragma unroll
            for (int j = 0; j < 4; j++) {
                int row = R0 + rt * 16 + lg * 4 + j;
                ybuf[row][c] = f2bf((r[rt][n0][j] - mu[rt][j]) * rs[rt][j] * g + bb);
            }
    }

    // ---- FF: h = relu(y@W1+b1) (4 chunks, prefetch), f = h@W2 accumulated ----
    bfrag yf[2][4];
#pragma unroll
    for (int rt = 0; rt < 2; rt++)
#pragma unroll
        for (int kk = 0; kk < 4; kk++)
            yf[rt][kk] = *(const bfrag*)&ybuf[R0 + rt * 16 + lr][kk * 32 + lg * 8];
    ffrag facc[2][8];
#pragma unroll
    for (int rt = 0; rt < 2; rt++)
#pragma unroll
        for (int n0 = 0; n0 < 8; n0++) facc[rt][n0] = ffrag{0.f, 0.f, 0.f, 0.f};
    for (int ch = 0; ch < 4; ++ch) {
        {
            bfrag bw[4], bwn[4];
#pragma unroll
            for (int kk = 0; kk < 4; kk++)
                bw[kk] = *(const bfrag*)(W1t + (ch * 128 + lr) * 128 + kk * 32 + lg * 8);
#pragma unroll
            for (int n0 = 0; n0 < 8; n0++) {
                if (n0 < 7) {
#pragma unroll
                    for (int kk = 0; kk < 4; kk++)
                        bwn[kk] = *(const bfrag*)(W1t + (ch * 128 + (n0 + 1) * 16 + lr) * 128 + kk * 32 + lg * 8);
                }
                ffrag c0 = {0.f, 0.f, 0.f, 0.f}, c1 = {0.f, 0.f, 0.f, 0.f};
#pragma unroll
                for (int kk = 0; kk < 4; kk++) {
                    c0 = MFMA(yf[0][kk], bw[kk], c0);
                    c1 = MFMA(yf[1][kk], bw[kk], c1);
                }
                float bb = b1[ch * 128 + n0 * 16 + lr];
#pragma unroll
                for (int j = 0; j < 4; j++) {
                    sbuf[R0 + lg * 4 + j][n0 * 16 + lr] = f2bf(fmaxf(c0[j] + bb, 0.f));
                    sbuf[R0 + 16 + lg * 4 + j][n0 * 16 + lr] = f2bf(fmaxf(c1[j] + bb, 0.f));
                }
                if (n0 < 7) {
#pragma unroll
                    for (int kk = 0; kk < 4; kk++) bw[kk] = bwn[kk];
                }
            }
        }
        bfrag hf[2][4];
#pragma unroll
        for (int rt = 0; rt < 2; rt++)
#pragma unroll
            for (int kk = 0; kk < 4; kk++)
                hf[rt][kk] = *(const bfrag*)&sbuf[R0 + rt * 16 + lr][kk * 32 + lg * 8];
#pragma unroll
        for (int n0 = 0; n0 < 8; n0++) {
#pragma unroll
            for (int kk = 0; kk < 4; kk++) {
                bfrag bw = *(const bfrag*)(W2t + (n0 * 16 + lr) * 512 + ch * 128 + kk * 32 + lg * 8);
                facc[0][n0] = MFMA(hf[0][kk], bw, facc[0][n0]);
                facc[1][n0] = MFMA(hf[1][kk], bw, facc[1][n0]);
            }
        }
    }

    // ---- residual2 (y bf16 from ybuf) + LN2 + store ----
#pragma unroll
    for (int n0 = 0; n0 < 8; n0++) {
        int c = n0 * 16 + lr;
        float bb = b2[c];
#pragma unroll
        for (int rt = 0; rt < 2; rt++)
#pragma unroll
            for (int j = 0; j < 4; j++) {
                int row = R0 + rt * 16 + lg * 4 + j;
                facc[rt][n0][j] = facc[rt][n0][j] + bf2f(ybuf[row][c]) + bb;
            }
    }
#pragma unroll
    for (int rt = 0; rt < 2; rt++)
#pragma unroll
        for (int j = 0; j < 4; j++) {
            float s1 = 0.f, s2 = 0.f;
#pragma unroll
            for (int n0 = 0; n0 < 8; n0++) { float v = facc[rt][n0][j]; s1 += v; s2 += v * v; }
#pragma unroll
            for (int d = 1; d < 16; d <<= 1) { s1 += __shfl_xor(s1, d); s2 += __shfl_xor(s2, d); }
            float m_ = s1 * (1.f / 128.f);
            mu[rt][j] = m_;
            rs[rt][j] = rsqrtf(s2 * (1.f / 128.f) - m_ * m_ + 1e-5f);
        }
#pragma unroll
    for (int n0 = 0; n0 < 8; n0++) {
        int c = n0 * 16 + lr;
        float g = ln2g[c], bb = ln2b[c];
#pragma unroll
        for (int rt = 0; rt < 2; rt++)
#pragma unroll
            for (int j = 0; j < 4; j++) {
                int row = R0 + rt * 16 + lg * 4 + j;
                out[(tok0 + row) * 128 + c] = (facc[rt][n0][j] - mu[rt][j]) * rs[rt][j] * g + bb;
            }
    }
}

extern "C" void kernel_launch(void* const* d_in, const int* in_sizes, int n_in,
                              void* d_out, int out_size, void* d_ws, size_t ws_size,
                              hipStream_t stream) {
    const float* x    = (const float*)d_in[0];
    const float* Wq   = (const float*)d_in[1];
    const float* Wk   = (const float*)d_in[2];
    const float* Wv   = (const float*)d_in[3];
    const float* Wo   = (const float*)d_in[4];
    const float* ln1g = (const float*)d_in[5];
    const float* ln1b = (const float*)d_in[6];
    const float* W1   = (const float*)d_in[7];
    const float* b1   = (const float*)d_in[8];
    const float* W2   = (const float*)d_in[9];
    const float* b2   = (const float*)d_in[10];
    const float* ln2g = (const float*)d_in[11];
    const float* ln2b = (const float*)d_in[12];
    float* out = (float*)d_out;

    // ws layout (~5.7 MB)
    short* partKV = (short*)d_ws;                       // 512*4*1024 bf16
    float* partKs = (float*)(partKV + 2097152);         // 512*4*128  f32
    short* KVt    = (short*)(partKs + 262144);          // 64*1024    bf16 [m][d]
    float* Ksf    = (float*)(KVt + 65536);              // 64*32      f32
    short* Wqt    = (short*)(Ksf + 2048);
    short* Wkt    = Wqt + 16384;
    short* Wvt    = Wkt + 16384;
    short* Wot    = Wvt + 16384;
    short* W1t    = Wot + 16384;                        // [512][128]
    short* W2t    = W1t + 65536;                        // [128][512]

    kw_conv<<<768, 256, 0, stream>>>(Wq, Wk, Wv, Wo, W1, W2, Wqt, Wkt, Wvt, Wot, W1t, W2t);
    k1_kv<<<512, 256, 0, stream>>>(x, Wkt, Wvt, partKV, partKs);
    k2_red<<<64, 256, 0, stream>>>(partKV, partKs, KVt, Ksf);
    k3_main<<<1024, 256, 0, stream>>>(x, Wqt, Wot, KVt, Ksf, ln1g, ln1b, W1t, b1,
                                      W2t, b2, ln2g, ln2b, out);
}